// Round 15
// baseline (453.756 us; speedup 1.0000x reference)
//
#include <hip/hip_runtime.h>
#include <math.h>

#ifndef M_PI
#define M_PI 3.14159265358979323846
#endif

static inline int cdiv(int a, int b){ return (a + b - 1) / b; }

#define SQRT3f  1.7320508075688772f
#define SQRT5f  2.23606797749979f
#define SQRT15f 3.872983346207417f
#define KRADf   0.6324555320336759f      /* sqrt(2/R_MAX), R_MAX=5 */
#define PI5f    0.6283185307179586f      /* pi/5 */
#define KPI5f   (KRADf * PI5f)
#define CSH2f   (0.5f*SQRT5f)            /* sh2[2] const */
#define CSH4f   (0.5f*SQRT15f)           /* sh2[4] const */

// ---------------------------------------------------------------------------
// R14: scatter store-layout fix landed (450.0us best; scatter out of top-5).
// THIS ROUND: 2-DEEP PREFETCH of the scalar node-gather (h0/dm0) in
// k_fwd_b0 / k_bwd_b1_col / k_bwd_b0_row (+1 reg each, 60->~62 VGPR).
// Mechanism: 35% VALU-idle with 0 conflicts & 9% HBM = partially exposed
// gather latency; 1-deep prefetch covers ~1 iteration (~150-200cy) vs
// ~300-400cy L2 latency when waves cluster. Value pipelined 2 iters,
// index 3. k_fwd_b1's 9-wide gather stays 1-deep (r9: +9 regs overflows).
// If neutral -> gather exposure bounded at ~0 -> declare plateau next.
// Rules carried: NO launch_bounds on edge kernels; NO scattered atomics;
// VGPR<=64 + FETCH/WRITE flat tripwire.
// ---------------------------------------------------------------------------

__device__ __forceinline__ float grp16_sum(float v){
  v += __shfl_xor(v, 1, 64);
  v += __shfl_xor(v, 2, 64);
  v += __shfl_xor(v, 4, 64);
  v += __shfl_xor(v, 8, 64);
  return v;
}
__device__ __forceinline__ float xgrp_sum(float v){    // across 4 edge-groups
  v += __shfl_xor(v, 16, 64);
  v += __shfl_xor(v, 32, 64);
  return v;
}

// raw second-order monomials: {xy, yz, 3z^2-1, xz, x^2-y^2}
__device__ __forceinline__ void base2_from_u(float ux, float uy, float uz, float* b2)
{
  float z2 = uz*uz, x2 = ux*ux, y2 = uy*uy;
  b2[0] = ux*uy;
  b2[1] = uy*uz;
  b2[2] = fmaf(z2, 3.f, -1.f);
  b2[3] = ux*uz;
  b2[4] = x2 - y2;
}

// ---------------------------------------------------------------------------
// Degree histogram (E-parallel)
// ---------------------------------------------------------------------------
__global__ void k_hist(const int* __restrict__ ei, int E,
                       int* __restrict__ deg_row, int* __restrict__ deg_col)
{
  int e = blockIdx.x * blockDim.x + threadIdx.x;
  if (e >= E) return;
  atomicAdd(&deg_row[ei[e]], 1);
  atomicAdd(&deg_col[ei[E + e]], 1);
}

// ---------------------------------------------------------------------------
// Scan-free segment allocation: wave-aggregated atomicAdd on global cursors.
// ---------------------------------------------------------------------------
__global__ void k_alloc(const int* __restrict__ deg_row, const int* __restrict__ deg_col,
                        int* __restrict__ start_row, int* __restrict__ cur_row,
                        int* __restrict__ start_col, int* __restrict__ cur_col,
                        int* __restrict__ cursors, int N)
{
  int idx = blockIdx.x * blockDim.x + threadIdx.x;
  int lane = threadIdx.x & 63;
  #pragma unroll
  for (int which = 0; which < 2; which++) {
    const int* deg = which ? deg_col : deg_row;
    int* start = which ? start_col : start_row;
    int* cur   = which ? cur_col   : cur_row;
    int v = (idx < N) ? deg[idx] : 0;
    int incl = v;
    #pragma unroll
    for (int d = 1; d < 64; d <<= 1) {
      int y = __shfl_up(incl, d, 64);
      if (lane >= d) incl += y;
    }
    int wtot = __shfl(incl, 63, 64);
    int base = 0;
    if (lane == 63) base = atomicAdd(&cursors[which], wtot);
    base = __shfl(base, 63, 64);
    if (idx < N) { int st = base + incl - v; start[idx] = st; cur[idx] = st; }
  }
}

// ---------------------------------------------------------------------------
// Scatter + compact geometry in BOTH CSR orders. Separate u/sc streams
// (independent lines, parallel stores) + merged idx int2 (one 8B store).
// ---------------------------------------------------------------------------
__global__ void k_scatter_geom(const float* __restrict__ pos, const int* __restrict__ ei, int E,
                               int* __restrict__ cur_row, int* __restrict__ cur_col,
                               float4* __restrict__ uR, float2* __restrict__ scR,
                               float4* __restrict__ uC, float2* __restrict__ scC,
                               int2* __restrict__ idxR, int2* __restrict__ idxC)
{
  int e = blockIdx.x * blockDim.x + threadIdx.x;
  if (e >= E) return;
  int row = ei[e], col = ei[E + e];
  int pr = atomicAdd(&cur_row[row], 1);
  int pc = atomicAdd(&cur_col[col], 1);
  idxR[pr] = make_int2(col, pc);
  idxC[pc] = make_int2(row, pr);

  float px = pos[row*3+0] - pos[col*3+0];
  float py = pos[row*3+1] - pos[col*3+1];
  float pz = pos[row*3+2] - pos[col*3+2];
  float r2 = px*px + py*py + pz*pz + 1e-12f;
  float r = sqrtf(r2);
  float inv_r = 1.0f / r;
  float ux = px*inv_r, uy = py*inv_r, uz = pz*inv_r;
  float s1, c1;
  sincosf(r * PI5f, &s1, &c1);
  float4 u4 = make_float4(ux, uy, uz, inv_r);
  float2 sc = make_float2(s1, c1);
  uR[pr] = u4; scR[pr] = sc;
  uC[pc] = u4; scC[pc] = sc;
}

// ---------------------------------------------------------------------------
// h0_init[n,:] = emb[z[n],:] @ W_init
// ---------------------------------------------------------------------------
__global__ void k_node_init(const float* __restrict__ emb, const int* __restrict__ z,
                            const float* __restrict__ W_init, float* __restrict__ h0, int N)
{
  __shared__ float sW[256];
  if (threadIdx.x < 256) sW[threadIdx.x] = W_init[threadIdx.x];
  __syncthreads();
  int n = blockIdx.x * blockDim.x + threadIdx.x;
  if (n >= N) return;
  const float* e = emb + z[n]*16;
  float ev[16];
  #pragma unroll
  for (int k = 0; k < 16; k++) ev[k] = e[k];
  #pragma unroll
  for (int c = 0; c < 16; c++) {
    float s = 0.f;
    #pragma unroll
    for (int k = 0; k < 16; k++) s += ev[k] * sW[k*16+c];
    h0[n*16+c] = s;
  }
}

// ---------------------------------------------------------------------------
// Forward block 0 — persistent wave per node, 16-lane; node-update folded;
// even/odd split Chebyshev; 2-deep h0 gather prefetch.
// ---------------------------------------------------------------------------
__global__ void k_fwd_b0(const float* __restrict__ Wr, const float* __restrict__ br,
                         const float* __restrict__ h0_in,
                         const float4* __restrict__ uR, const float2* __restrict__ scR,
                         const int2* __restrict__ idxR,
                         const int* __restrict__ start_row, const int* __restrict__ deg_row,
                         const float* __restrict__ U,      // W_out block0: U0|U1|U2
                         float* __restrict__ h0_out, float* __restrict__ h1_out,
                         float* __restrict__ h2_out, int N)
{
  __shared__ float sU[768];
  for (int t = threadIdx.x; t < 768; t += blockDim.x) sU[t] = U[t];
  __syncthreads();

  int wid = (blockIdx.x * blockDim.x + threadIdx.x) >> 6;
  int nw  = (gridDim.x * blockDim.x) >> 6;
  int lane = threadIdx.x & 63;
  int g = lane >> 4, c = lane & 15;
  int gbase = lane & 48;
  float wr0[8], wr1[8], wr2[8];
  #pragma unroll
  for (int k = 0; k < 8; k++) {
    wr0[k] = Wr[k*80 + c];
    wr1[k] = Wr[k*80 + 16 + c];
    wr2[k] = Wr[k*80 + 32 + c];
  }
  float b0v = br[c], b1v = br[16 + c], b2v = br[32 + c];

  for (int n = wid; n < N; n += nw) {
    float acc0 = 0.f, acc1[3] = {0.f,0.f,0.f}, acc2[5] = {0.f,0.f,0.f,0.f,0.f};

    int i0 = start_row[n] + g, i1 = start_row[n] + deg_row[n];
    float4 Un = {0,0,0,0}; float2 SCn = {0,0};
    float h0_cur = 0.f, h0_nxt = 0.f; int cC = 0;
    if (i0 < i1) {
      int cA = idxR[i0].x;
      Un = uR[i0]; SCn = scR[i0];
      h0_cur = h0_in[cA*16 + c];
      if (i0+4 < i1) {
        int cB = idxR[i0+4].x;
        h0_nxt = h0_in[cB*16 + c];
      }
      cC = (i0+8 < i1) ? idxR[i0+8].x : 0;
    }
    for (int i = i0; i < i1; i += 4) {
      float4 U4 = Un; float2 SC = SCn;
      float h0c = h0_cur;
      h0_cur = h0_nxt;                      // value pipelined 2 deep
      if (i+8 < i1) {
        h0_nxt = h0_in[cC*16 + c];          // issue gather 2 iters ahead
        cC = (i+12 < i1) ? idxR[i+12].x : 0;
      }
      if (i+4 < i1) {
        Un = uR[i+4]; SCn = scR[i+4];
      }
      // even/odd Chebyshev + w-dot: chains A={s1,s3,s5,s7}, B={s2,s4,s6,s8}
      float Ki = KRADf * U4.w;
      float tc = 2.f * SC.y;
      float c2m = fmaf(tc, tc, -2.f);     // 2*cos(2θ)
      float sA = SC.x, sAp = -SC.x;       // s1, s_{-1}
      float sB = tc * SC.x, sBp = 0.f;    // s2, s0
      float w0 = b0v, w1 = b1v, w2 = b2v;
      #pragma unroll
      for (int j = 0; j < 4; j++) {
        float radA = Ki * sA;
        float radB = Ki * sB;
        w0 += radA*wr0[2*j] + radB*wr0[2*j+1];
        w1 += radA*wr1[2*j] + radB*wr1[2*j+1];
        w2 += radA*wr2[2*j] + radB*wr2[2*j+1];
        float sAn = fmaf(c2m, sA, -sAp); sAp = sA; sA = sAn;
        float sBn = fmaf(c2m, sB, -sBp); sBp = sB; sB = sBn;
      }
      float b2m[5];
      base2_from_u(U4.x, U4.y, U4.z, b2m);
      acc0 += w0*h0c;
      float wh1 = w1*h0c, wh2 = w2*h0c;
      acc1[0] += wh1*U4.x; acc1[1] += wh1*U4.y; acc1[2] += wh1*U4.z;
      #pragma unroll
      for (int m = 0; m < 5; m++) acc2[m] += wh2*b2m[m];
    }
    acc0 = xgrp_sum(acc0);
    #pragma unroll
    for (int m = 0; m < 3; m++) acc1[m] = xgrp_sum(acc1[m]);
    #pragma unroll
    for (int m = 0; m < 5; m++) acc2[m] = xgrp_sum(acc2[m]);

    // ---- folded node update, component-at-a-time.
    {
      float o = 0.f;
      #pragma unroll
      for (int j = 0; j < 4; j++) {
        int cs = (g << 2) + j;
        o = fmaf(__shfl(acc0, gbase + cs, 64), sU[cs*16 + c], o);
      }
      o = xgrp_sum(o);
      if (g == 0) h0_out[n*16 + c] = h0_in[n*16 + c] + o;
    }
    #pragma unroll
    for (int m = 0; m < 3; m++) {
      float o = 0.f;
      #pragma unroll
      for (int j = 0; j < 4; j++) {
        int cs = (g << 2) + j;
        o = fmaf(__shfl(acc1[m], gbase + cs, 64), sU[256 + cs*16 + c], o);
      }
      o = xgrp_sum(o);
      if (g == 1) h1_out[n*48 + c*3 + m] = SQRT3f*o;
    }
    #pragma unroll
    for (int m = 0; m < 5; m++) {
      float o = 0.f;
      #pragma unroll
      for (int j = 0; j < 4; j++) {
        int cs = (g << 2) + j;
        o = fmaf(__shfl(acc2[m], gbase + cs, 64), sU[512 + cs*16 + c], o);
      }
      o = xgrp_sum(o);
      if (g == 2) {
        const float csh[5] = {SQRT15f, SQRT15f, CSH2f, SQRT15f, CSH4f};
        h2_out[n*80 + c*5 + m] = csh[m]*o;
      }
    }
  }
}

// ---------------------------------------------------------------------------
// Forward block 1 (last) — persistent wave per node, 16-lane, pipelined idx;
// even/odd split Chebyshev. Gather stays 1-deep (9-wide; 2-deep = +9 regs).
// ---------------------------------------------------------------------------
__global__ void k_fwd_b1(const float* __restrict__ Wr, const float* __restrict__ br,
                         const float* __restrict__ h0_in, const float* __restrict__ h1_in,
                         const float* __restrict__ h2_in,
                         const float4* __restrict__ uR, const float2* __restrict__ scR,
                         const int2* __restrict__ idxR,
                         const int* __restrict__ start_row, const int* __restrict__ deg_row,
                         float* __restrict__ a0, int N)
{
  int wid = (blockIdx.x * blockDim.x + threadIdx.x) >> 6;
  int nw  = (gridDim.x * blockDim.x) >> 6;
  int lane = threadIdx.x & 63;
  int g = lane >> 4, c = lane & 15;
  float wr0[8], wr3[8], wr4[8];
  #pragma unroll
  for (int k = 0; k < 8; k++) {
    wr0[k] = Wr[k*80 + c];
    wr3[k] = SQRT3f*Wr[k*80 + 48 + c];   // SQRT3 fold: w3' = SQRT3*w3
    wr4[k] = Wr[k*80 + 64 + c];
  }
  float b0v = br[c], b3v = SQRT3f*br[48 + c], b4v = br[64 + c];

  for (int n = wid; n < N; n += nw) {
    float acc0 = 0.f;
    int i0 = start_row[n] + g, i1 = start_row[n] + deg_row[n];
    float4 Un = {0,0,0,0}; float2 SCn = {0,0};
    float h0n = 0.f, h1n[3] = {0,0,0}, h2n[5] = {0,0,0,0,0};
    int cB = 0;
    if (i0 < i1) {
      int cA = idxR[i0].x;
      cB = (i0+4 < i1) ? idxR[i0+4].x : 0;
      Un = uR[i0]; SCn = scR[i0];
      h0n = h0_in[cA*16 + c];
      #pragma unroll
      for (int m = 0; m < 3; m++) h1n[m] = h1_in[cA*48 + c*3 + m];
      #pragma unroll
      for (int m = 0; m < 5; m++) h2n[m] = h2_in[cA*80 + c*5 + m];
    }
    for (int i = i0; i < i1; i += 4) {
      float4 U = Un; float2 SC = SCn;
      float h0c = h0n;
      float h1c[3], h2c[5];
      #pragma unroll
      for (int m = 0; m < 3; m++) h1c[m] = h1n[m];
      #pragma unroll
      for (int m = 0; m < 5; m++) h2c[m] = h2n[m];
      if (i+4 < i1) {
        Un = uR[i+4]; SCn = scR[i+4];
        h0n = h0_in[cB*16 + c];
        #pragma unroll
        for (int m = 0; m < 3; m++) h1n[m] = h1_in[cB*48 + c*3 + m];
        #pragma unroll
        for (int m = 0; m < 5; m++) h2n[m] = h2_in[cB*80 + c*5 + m];
        cB = (i+8 < i1) ? idxR[i+8].x : 0;
      }
      // even/odd Chebyshev + w-dot
      float Ki = KRADf * U.w;
      float tc = 2.f * SC.y;
      float c2m = fmaf(tc, tc, -2.f);
      float sA = SC.x, sAp = -SC.x;
      float sB = tc * SC.x, sBp = 0.f;
      float w0 = b0v, w3 = b3v, w4 = b4v;
      #pragma unroll
      for (int j = 0; j < 4; j++) {
        float radA = Ki * sA;
        float radB = Ki * sB;
        w0 += radA*wr0[2*j] + radB*wr0[2*j+1];
        w3 += radA*wr3[2*j] + radB*wr3[2*j+1];
        w4 += radA*wr4[2*j] + radB*wr4[2*j+1];
        float sAn = fmaf(c2m, sA, -sAp); sAp = sA; sA = sAn;
        float sBn = fmaf(c2m, sB, -sBp); sBp = sB; sB = sBn;
      }
      float b2[5];
      base2_from_u(U.x, U.y, U.z, b2);
      float S1 = h1c[0]*U.x + h1c[1]*U.y + h1c[2]*U.z;   // SQRT3 folded in w3
      float A  = h2c[0]*b2[0] + h2c[1]*b2[1] + h2c[3]*b2[3];
      float B  = CSH2f*(h2c[2]*b2[2]) + CSH4f*(h2c[4]*b2[4]);
      float S2 = fmaf(SQRT15f, A, B);
      acc0 += w0*h0c + w3*S1 + w4*S2;
    }
    acc0 = xgrp_sum(acc0);
    if (g == 0) a0[n*16 + c] = acc0;
  }
}

// ---------------------------------------------------------------------------
// Readout fwd + bwd fused (unchanged).
// ---------------------------------------------------------------------------
__global__ void __launch_bounds__(256, 1)
k_readout_bwd(const float* __restrict__ h0s1, const float* __restrict__ a0in,
              const float* __restrict__ W_read,
              const float* __restrict__ W1, const float* __restrict__ b1,
              const float* __restrict__ W2, const float* __restrict__ b2,
              const float* __restrict__ U0b1,
              float* __restrict__ g0, float* __restrict__ ga0,
              float* __restrict__ partials, int N)
{
  __shared__ float sWr[256], sW1[256], sU[256], sb1[16], sW2[16], sb2;
  __shared__ float swave[4];
  {
    int t = threadIdx.x;
    if (t < 256) { sWr[t] = W_read[t]; sW1[t] = W1[t]; sU[t] = U0b1[t]; }
    if (t < 16)  { sb1[t] = b1[t]; sW2[t] = W2[t]; }
    if (t == 0)  sb2 = b2[0];
  }
  __syncthreads();
  int n = blockIdx.x * blockDim.x + threadIdx.x;
  float site = 0.f;
  if (n < N) {
    float h[16], av[16], inv[16], dt[16], g0v[16];
    #pragma unroll
    for (int d = 0; d < 16; d++) av[d] = a0in[n*16 + d];
    #pragma unroll
    for (int d = 0; d < 16; d++) {
      float s = h0s1[n*16 + d];
      #pragma unroll
      for (int cc = 0; cc < 16; cc++) s += av[cc] * sU[cc*16 + d];
      h[d] = s;
    }
    #pragma unroll
    for (int j = 0; j < 16; j++) {
      float s = 0.f;
      #pragma unroll
      for (int d = 0; d < 16; d++) s += h[d] * sWr[d*16 + j];
      inv[j] = s;
    }
    site = sb2;
    #pragma unroll
    for (int c = 0; c < 16; c++) {
      float t = sb1[c];
      #pragma unroll
      for (int j = 0; j < 16; j++) t += inv[j] * sW1[j*16 + c];
      float sg = 1.f / (1.f + expf(-t));
      float w2v = sW2[c];
      site += t * sg * w2v;
      dt[c] = w2v * sg * (1.f + t * (1.f - sg));
    }
    float dinv[16];
    #pragma unroll
    for (int j = 0; j < 16; j++) {
      float s = 0.f;
      #pragma unroll
      for (int c = 0; c < 16; c++) s += dt[c] * sW1[j*16 + c];
      dinv[j] = s;
    }
    #pragma unroll
    for (int d = 0; d < 16; d++) {
      float s = 0.f;
      #pragma unroll
      for (int j = 0; j < 16; j++) s += dinv[j] * sWr[d*16 + j];
      g0v[d] = s;
      g0[n*16 + d] = s;
    }
    #pragma unroll
    for (int c = 0; c < 16; c++) {
      float s = 0.f;
      #pragma unroll
      for (int d = 0; d < 16; d++) s += g0v[d] * sU[c*16 + d];
      ga0[n*16 + c] = s;
    }
  }
  #pragma unroll
  for (int off = 32; off; off >>= 1) site += __shfl_down(site, off, 64);
  int wave = threadIdx.x >> 6;
  if ((threadIdx.x & 63) == 0) swave[wave] = site;
  __syncthreads();
  if (threadIdx.x == 0)
    partials[blockIdx.x] = swave[0] + swave[1] + swave[2] + swave[3];
}

// Sum per-block partials into energy (single tiny block).
__global__ void k_energy(const float* __restrict__ partials, int nb,
                         float* __restrict__ energy)
{
  int t = threadIdx.x;           // 128 threads (2 waves)
  float s = 0.f;
  for (int i = t; i < nb; i += 128) s += partials[i];
  #pragma unroll
  for (int off = 32; off; off >>= 1) s += __shfl_down(s, off, 64);
  __shared__ float sw[2];
  if ((t & 63) == 0) sw[t >> 6] = s;
  __syncthreads();
  if (t == 0) energy[0] = sw[0] + sw[1];
}

// ---------------------------------------------------------------------------
// ga = g @ U^T (full, for block 0 backward).
// ---------------------------------------------------------------------------
__global__ void k_ga(const float* __restrict__ g0, const float* __restrict__ g1,
                     const float* __restrict__ g2, const float* __restrict__ U,
                     float* __restrict__ ga0, float* __restrict__ ga1, float* __restrict__ ga2,
                     int N)
{
  int idx = blockIdx.x * blockDim.x + threadIdx.x;
  int n = idx >> 4, c = idx & 15;
  if (n >= N) return;
  const float* U0 = U;
  const float* U1 = U + 256;
  const float* U2 = U + 512;
  float s = 0.f;
  #pragma unroll
  for (int d = 0; d < 16; d++) s += g0[n*16 + d] * U0[c*16 + d];
  ga0[n*16 + c] = s;
  float v1[3] = {0.f, 0.f, 0.f};
  #pragma unroll
  for (int d = 0; d < 16; d++) {
    float u = U1[c*16 + d];
    #pragma unroll
    for (int m = 0; m < 3; m++) v1[m] += g1[n*48 + d*3 + m] * u;
  }
  #pragma unroll
  for (int m = 0; m < 3; m++) ga1[n*48 + c*3 + m] = v1[m];
  float v2[5] = {0.f, 0.f, 0.f, 0.f, 0.f};
  #pragma unroll
  for (int d = 0; d < 16; d++) {
    float u = U2[c*16 + d];
    #pragma unroll
    for (int m = 0; m < 5; m++) v2[m] += g2[n*80 + d*5 + m] * u;
  }
  #pragma unroll
  for (int m = 0; m < 5; m++) ga2[n*80 + c*5 + m] = v2[m];
}

// ---------------------------------------------------------------------------
// Backward block 1, col-centric — persistent wave per node, 16-lane;
// 2-deep dm0 gather prefetch.
// ---------------------------------------------------------------------------
__global__ void k_bwd_b1_col(const float* __restrict__ Wr, const float* __restrict__ br,
                             const float* __restrict__ h0_in, const float* __restrict__ h1_in,
                             const float* __restrict__ h2_in,
                             const float* __restrict__ ga0,
                             const float4* __restrict__ uC, const float2* __restrict__ scC,
                             const int2* __restrict__ idxC,
                             const int* __restrict__ start_col, const int* __restrict__ deg_col,
                             float* __restrict__ g0, float* __restrict__ g1, float* __restrict__ g2,
                             float* __restrict__ dv_col, int N)
{
  int wid = (blockIdx.x * blockDim.x + threadIdx.x) >> 6;
  int nw  = (gridDim.x * blockDim.x) >> 6;
  int lane = threadIdx.x & 63;
  int g = lane >> 4, c = lane & 15;
  float wr0[8], wr3[8], wr4[8];
  #pragma unroll
  for (int k = 0; k < 8; k++) {
    wr0[k] = Wr[k*80 + c];
    wr3[k] = Wr[k*80 + 48 + c];
    wr4[k] = Wr[k*80 + 64 + c];
  }
  float b0v = br[c], b3v = br[48 + c], b4v = br[64 + c];

  for (int n = wid; n < N; n += nw) {
    float h0c = h0_in[n*16 + c];
    float h1s[3], h2s[5];
    #pragma unroll
    for (int m = 0; m < 3; m++) h1s[m] = SQRT3f * h1_in[n*48 + c*3 + m];
    h2s[0] = SQRT15f * h2_in[n*80 + c*5 + 0];
    h2s[1] = SQRT15f * h2_in[n*80 + c*5 + 1];
    h2s[2] = CSH2f   * h2_in[n*80 + c*5 + 2];
    h2s[3] = SQRT15f * h2_in[n*80 + c*5 + 3];
    h2s[4] = CSH4f   * h2_in[n*80 + c*5 + 4];

    float accg0 = 0.f, accg1[3] = {0.f,0.f,0.f}, accg2[5] = {0.f,0.f,0.f,0.f,0.f};

    int i0 = start_col[n] + g, i1 = start_col[n] + deg_col[n];
    float4 Un = {0,0,0,0}; float2 SCn = {0,0};
    float dm_cur = 0.f, dm_nxt = 0.f; int rC = 0;
    if (i0 < i1) {
      int rA = idxC[i0].x;
      Un = uC[i0]; SCn = scC[i0];
      dm_cur = ga0[rA*16 + c];
      if (i0+4 < i1) {
        int rB = idxC[i0+4].x;
        dm_nxt = ga0[rB*16 + c];
      }
      rC = (i0+8 < i1) ? idxC[i0+8].x : 0;
    }
    for (int i = i0; i < i1; i += 4) {
      float4 U4 = Un; float2 SC = SCn;
      float dm0 = dm_cur;
      dm_cur = dm_nxt;                      // value pipelined 2 deep
      if (i+8 < i1) {
        dm_nxt = ga0[rC*16 + c];            // issue gather 2 iters ahead
        rC = (i+12 < i1) ? idxC[i+12].x : 0;
      }
      if (i+4 < i1) {
        Un = uC[i+4]; SCn = scC[i+4];
      }
      float ux = U4.x, uy = U4.y, uz = U4.z, inv_r = U4.w;
      float b2[5];
      base2_from_u(ux, uy, uz, b2);

      float S1 = h1s[0]*ux + h1s[1]*uy + h1s[2]*uz;
      float S2 = h2s[0]*b2[0] + h2s[1]*b2[1] + h2s[2]*b2[2]
               + h2s[3]*b2[3] + h2s[4]*b2[4];

      float dw0 = dm0 * h0c;
      float dw3 = dm0 * S1;
      float dw4 = dm0 * S2;

      // merged Chebyshev + w-dot + t-dot + P/Q
      float Ki = KRADf * inv_r;
      float tcv = 2.f * SC.y;
      float sprev = 0.f, s = SC.x, cprev = 1.f, cc = SC.y;
      float w0 = b0v, w3 = b3v, w4 = b4v;
      float P = 0.f, Q = 0.f;
      #pragma unroll
      for (int k = 0; k < 8; k++) {
        float rad = Ki * s;
        w0 += rad*wr0[k]; w3 += rad*wr3[k]; w4 += rad*wr4[k];
        float t = dw0*wr0[k] + dw3*wr3[k] + dw4*wr4[k];
        P = fmaf(t*cc, (float)(k+1), P);
        Q = fmaf(t, rad, Q);
        float sn = tcv*s - sprev; sprev = s; s = sn;
        float cn = tcv*cc - cprev; cprev = cc; cc = cn;
      }

      float t3 = dm0 * w3, t4 = dm0 * w4;
      accg0 += dm0 * w0;
      accg1[0] += t3*ux; accg1[1] += t3*uy; accg1[2] += t3*uz;
      #pragma unroll
      for (int m = 0; m < 5; m++) accg2[m] += t4*b2[m];

      float q1x = t3*h1s[0], q1y = t3*h1s[1], q1z = t3*h1s[2];
      float q0 = t4*h2s[0], q1 = t4*h2s[1], q2 = t4*h2s[2], q3 = t4*h2s[3], q4 = t4*h2s[4];
      float q4d = q4 + q4;
      float q2h = 6.f*q2;
      float gr = (KPI5f*P - Q) * inv_r;
      float gux = q1x + uy*q0 + uz*q3 + ux*q4d;
      float guy = q1y + ux*q0 + uz*q1 - uy*q4d;
      float guz = q1z + uy*q1 + uz*q2h + ux*q3;

      gr  = grp16_sum(gr);
      gux = grp16_sum(gux);
      guy = grp16_sum(guy);
      guz = grp16_sum(guz);

      if (c == 0) {
        float gdotu = gux*ux + guy*uy + guz*uz;
        dv_col[i*3+0] = gr*ux + (gux - gdotu*ux)*inv_r;
        dv_col[i*3+1] = gr*uy + (guy - gdotu*uy)*inv_r;
        dv_col[i*3+2] = gr*uz + (guz - gdotu*uz)*inv_r;
      }
    }
    accg0 = xgrp_sum(accg0);
    #pragma unroll
    for (int m = 0; m < 3; m++) accg1[m] = xgrp_sum(accg1[m]);
    #pragma unroll
    for (int m = 0; m < 5; m++) accg2[m] = xgrp_sum(accg2[m]);
    if (g == 0) {
      g0[n*16 + c] += accg0;
      g1[n*48 + c*3 + 0] = SQRT3f*accg1[0];
      g1[n*48 + c*3 + 1] = SQRT3f*accg1[1];
      g1[n*48 + c*3 + 2] = SQRT3f*accg1[2];
      g2[n*80 + c*5 + 0] = SQRT15f*accg2[0];
      g2[n*80 + c*5 + 1] = SQRT15f*accg2[1];
      g2[n*80 + c*5 + 2] = CSH2f  *accg2[2];
      g2[n*80 + c*5 + 3] = SQRT15f*accg2[3];
      g2[n*80 + c*5 + 4] = CSH4f  *accg2[4];
    }
  }
}

// ---------------------------------------------------------------------------
// Backward block 0, row-centric — persistent wave per node, 16-lane;
// even/odd sin+cos split; 2-deep h0 gather prefetch.
// ---------------------------------------------------------------------------
__global__ void k_bwd_b0_row(const float* __restrict__ Wr, const float* __restrict__ br,
                             const float* __restrict__ h0_in,
                             const float* __restrict__ ga0, const float* __restrict__ ga1,
                             const float* __restrict__ ga2,
                             const float4* __restrict__ uR, const float2* __restrict__ scR,
                             const int2* __restrict__ idxR,
                             const int* __restrict__ start_row, const int* __restrict__ deg_row,
                             float* __restrict__ dv_row, int N)
{
  int wid = (blockIdx.x * blockDim.x + threadIdx.x) >> 6;
  int nw  = (gridDim.x * blockDim.x) >> 6;
  int lane = threadIdx.x & 63;
  int g = lane >> 4, c = lane & 15;
  float wr0[8], wr1[8], wr2[8];
  #pragma unroll
  for (int k = 0; k < 8; k++) {
    wr0[k] = Wr[k*80 + c];
    wr1[k] = Wr[k*80 + 16 + c];
    wr2[k] = Wr[k*80 + 32 + c];
  }
  float b1v = br[16 + c], b2v = br[32 + c];

  for (int n = wid; n < N; n += nw) {
    float dm0 = ga0[n*16 + c];
    float dm1s[3], dm2s[5];
    #pragma unroll
    for (int m = 0; m < 3; m++) dm1s[m] = SQRT3f * ga1[n*48 + c*3 + m];
    dm2s[0] = SQRT15f * ga2[n*80 + c*5 + 0];
    dm2s[1] = SQRT15f * ga2[n*80 + c*5 + 1];
    dm2s[2] = CSH2f   * ga2[n*80 + c*5 + 2];
    dm2s[3] = SQRT15f * ga2[n*80 + c*5 + 3];
    dm2s[4] = CSH4f   * ga2[n*80 + c*5 + 4];

    int i0 = start_row[n] + g, i1 = start_row[n] + deg_row[n];
    float4 Un = {0,0,0,0}; float2 SCn = {0,0};
    float h0_cur = 0.f, h0_nxt = 0.f; int cC = 0;
    if (i0 < i1) {
      int cA = idxR[i0].x;
      Un = uR[i0]; SCn = scR[i0];
      h0_cur = h0_in[cA*16 + c];
      if (i0+4 < i1) {
        int cB = idxR[i0+4].x;
        h0_nxt = h0_in[cB*16 + c];
      }
      cC = (i0+8 < i1) ? idxR[i0+8].x : 0;
    }
    for (int i = i0; i < i1; i += 4) {
      float4 U = Un; float2 SC = SCn;
      float h0c = h0_cur;
      h0_cur = h0_nxt;                      // value pipelined 2 deep
      if (i+8 < i1) {
        h0_nxt = h0_in[cC*16 + c];          // issue gather 2 iters ahead
        cC = (i+12 < i1) ? idxR[i+12].x : 0;
      }
      if (i+4 < i1) {
        Un = uR[i+4]; SCn = scR[i+4];
      }
      float ux = U.x, uy = U.y, uz = U.z, inv_r = U.w;
      float b2[5];
      base2_from_u(ux, uy, uz, b2);

      float T1 = dm1s[0]*ux + dm1s[1]*uy + dm1s[2]*uz;
      float T2 = dm2s[0]*b2[0] + dm2s[1]*b2[1] + dm2s[2]*b2[2]
               + dm2s[3]*b2[3] + dm2s[4]*b2[4];

      float dw0 = dm0 * h0c;
      float dw1 = h0c * T1;
      float dw2 = h0c * T2;

      // even/odd merged Chebyshev (sin+cos) + w-dot + t-dot + P/Q.
      float Ki = KRADf * inv_r;
      float tcv = 2.f * SC.y;
      float c2m = fmaf(tcv, tcv, -2.f);        // 2*cos(2θ)
      float sA = SC.x,        sAp = -SC.x;     // s1, s_{-1}
      float cA = SC.y,        cAp =  SC.y;     // c1, c_{-1}
      float sB = tcv * SC.x,  sBp = 0.f;       // s2, s0
      float cB2 = fmaf(tcv, SC.y, -1.f), cBp = 1.f;  // c2, c0
      float w1 = b1v, w2v = b2v;
      float P = 0.f, Q = 0.f;
      #pragma unroll
      for (int j = 0; j < 4; j++) {
        float radA = Ki * sA;
        float radB = Ki * sB;
        w1  += radA*wr1[2*j] + radB*wr1[2*j+1];
        w2v += radA*wr2[2*j] + radB*wr2[2*j+1];
        float tA = dw0*wr0[2*j]   + dw1*wr1[2*j]   + dw2*wr2[2*j];
        float tB = dw0*wr0[2*j+1] + dw1*wr1[2*j+1] + dw2*wr2[2*j+1];
        P = fmaf(tA*cA, (float)(2*j+1), P);
        P = fmaf(tB*cB2, (float)(2*j+2), P);
        Q = fmaf(tA, radA, Q);
        Q = fmaf(tB, radB, Q);
        float sAn = fmaf(c2m, sA, -sAp); sAp = sA; sA = sAn;
        float cAn = fmaf(c2m, cA, -cAp); cAp = cA; cA = cAn;
        float sBn = fmaf(c2m, sB, -sBp); sBp = sB; sB = sBn;
        float cBn = fmaf(c2m, cB2, -cBp); cBp = cB2; cB2 = cBn;
      }

      float w1h = w1*h0c, w2h = w2v*h0c;
      float q1x = dm1s[0]*w1h, q1y = dm1s[1]*w1h, q1z = dm1s[2]*w1h;
      float q0 = dm2s[0]*w2h, q1 = dm2s[1]*w2h, q2 = dm2s[2]*w2h, q3 = dm2s[3]*w2h, q4 = dm2s[4]*w2h;
      float q4d = q4 + q4;
      float q2h = 6.f*q2;
      float gr = (KPI5f*P - Q) * inv_r;
      float gux = q1x + uy*q0 + uz*q3 + ux*q4d;
      float guy = q1y + ux*q0 + uz*q1 - uy*q4d;
      float guz = q1z + uy*q1 + uz*q2h + ux*q3;

      gr  = grp16_sum(gr);
      gux = grp16_sum(gux);
      guy = grp16_sum(guy);
      guz = grp16_sum(guz);

      if (c == 0) {
        float gdotu = gux*ux + guy*uy + guz*uz;
        dv_row[i*3+0] = gr*ux + (gux - gdotu*ux)*inv_r;
        dv_row[i*3+1] = gr*uy + (guy - gdotu*uy)*inv_r;
        dv_row[i*3+2] = gr*uz + (guz - gdotu*uz)*inv_r;
      }
    }
  }
}

// ---------------------------------------------------------------------------
// Force assembly: 16 lanes per node, coalesced dv-stream reads, no atomics.
// cpos = idxR[i].y ; rpos = idxC[i].y.
// ---------------------------------------------------------------------------
__global__ void k_force(const int* __restrict__ start_row, const int* __restrict__ deg_row,
                        const int2* __restrict__ idxR,
                        const int* __restrict__ start_col, const int* __restrict__ deg_col,
                        const int2* __restrict__ idxC,
                        const float* __restrict__ dv_col, const float* __restrict__ dv_row,
                        float* __restrict__ force, int N)
{
  int idx = blockIdx.x * blockDim.x + threadIdx.x;
  int n = idx >> 4, l = idx & 15;
  if (n >= N) return;
  float fx = 0.f, fy = 0.f, fz = 0.f;
  int c0 = start_col[n], c1 = c0 + deg_col[n];
  for (int i = c0 + l; i < c1; i += 16) {
    int rp = idxC[i].y;
    fx += dv_col[i*3+0] + dv_row[rp*3+0];
    fy += dv_col[i*3+1] + dv_row[rp*3+1];
    fz += dv_col[i*3+2] + dv_row[rp*3+2];
  }
  int r0 = start_row[n], r1 = r0 + deg_row[n];
  for (int i = r0 + l; i < r1; i += 16) {
    int cp = idxR[i].y;
    fx -= dv_row[i*3+0] + dv_col[cp*3+0];
    fy -= dv_row[i*3+1] + dv_col[cp*3+1];
    fz -= dv_row[i*3+2] + dv_col[cp*3+2];
  }
  fx = grp16_sum(fx); fy = grp16_sum(fy); fz = grp16_sum(fz);
  if (l == 0) {
    force[n*3+0] = fx; force[n*3+1] = fy; force[n*3+2] = fz;
  }
}

// ---------------------------------------------------------------------------
extern "C" void kernel_launch(void* const* d_in, const int* in_sizes, int n_in,
                              void* d_out, int out_size, void* d_ws, size_t ws_size,
                              hipStream_t stream)
{
  const float* pos    = (const float*)d_in[0];
  const int*   z      = (const int*)  d_in[1];
  const int*   ei     = (const int*)  d_in[2];
  const float* emb    = (const float*)d_in[3];
  const float* W_init = (const float*)d_in[4];
  const float* Wr     = (const float*)d_in[5];   // (2, 8, 80)
  const float* br     = (const float*)d_in[6];   // (2, 80)
  const float* W_out  = (const float*)d_in[7];   // (2, 3, 16, 16)
  const float* W_read = (const float*)d_in[8];
  const float* W1     = (const float*)d_in[9];
  const float* b1     = (const float*)d_in[10];
  const float* W2     = (const float*)d_in[11];
  const float* b2     = (const float*)d_in[12];

  const int N = in_sizes[0] / 3;
  const int E = in_sizes[2] / 2;

  const int BLK = 256;
  const int NB_READOUT = cdiv(N, BLK);
  // Persistent grid for wave-per-node kernels.
  const int PBLK = (N < 8192) ? cdiv(N, 4) : 2048;

  float* f = (float*)d_ws;
  float4* uR  = (float4*)f; f += (size_t)E*4;
  float4* uC  = (float4*)f; f += (size_t)E*4;
  float2* scR = (float2*)f; f += (size_t)E*2;
  float2* scC = (float2*)f; f += (size_t)E*2;
  float* h0_s0 = f; f += (size_t)N*16;
  float* h0_s1 = f; f += (size_t)N*16;
  float* h1_s1 = f; f += (size_t)N*48;
  float* h2_s1 = f; f += (size_t)N*80;
  float* a0    = f; f += (size_t)N*16;   // fwd_b1 agg, then ga0 for bwd_b0
  float* a1    = f; f += (size_t)N*48;   // ga1
  float* a2    = f; f += (size_t)N*80;   // ga2
  float* ga0b1 = f; f += (size_t)N*16;   // readout's ga0 (dE/da0 block 1)
  float* g0    = f; f += (size_t)N*16;
  float* g1    = f; f += (size_t)N*48;
  float* g2    = f; f += (size_t)N*80;
  float* dv_c  = f; f += (size_t)E*3;    // dv from bwd b1, col order
  float* dv_r  = f; f += (size_t)E*3;    // dv from bwd b0, row order
  float* partials = f; f += (size_t)NB_READOUT;
  int* ip = (int*)f;
  int* cursors   = ip; ip += 2;          // cursors+deg contiguous -> one memset
  int* deg_row   = ip; ip += N;
  int* deg_col   = ip; ip += N;
  int* start_row = ip; ip += N;
  int* start_col = ip; ip += N;
  int* cur_row   = ip; ip += N;
  int* cur_col   = ip; ip += N;
  int2* idxR     = (int2*)ip; ip += (size_t)E*2;  // (col, cpos)
  int2* idxC     = (int2*)ip; ip += (size_t)E*2;  // (row, rpos)

  float* out    = (float*)d_out;
  float* energy = out;
  float* force  = out + 1;

  (void)hipMemsetAsync(cursors, 0, (size_t)(2 + 2*N) * sizeof(int), stream);

  // ---- CSR build (scan-free) + compact geometry in both orders ----
  k_hist<<<cdiv(E, BLK), BLK, 0, stream>>>(ei, E, deg_row, deg_col);
  k_alloc<<<cdiv(N, BLK), BLK, 0, stream>>>(deg_row, deg_col, start_row, cur_row,
                                            start_col, cur_col, cursors, N);
  k_scatter_geom<<<cdiv(E, BLK), BLK, 0, stream>>>(pos, ei, E, cur_row, cur_col,
                                                   uR, scR, uC, scC, idxR, idxC);

  k_node_init<<<cdiv(N, BLK), BLK, 0, stream>>>(emb, z, W_init, h0_s0, N);

  // ---- forward block 0 (node update folded into epilogue) ----
  k_fwd_b0<<<PBLK, BLK, 0, stream>>>(Wr, br, h0_s0, uR, scR, idxR,
                                     start_row, deg_row, W_out,
                                     h0_s1, h1_s1, h2_s1, N);

  // ---- forward block 1 (h0_s2 folded into readout) ----
  k_fwd_b1<<<PBLK, BLK, 0, stream>>>(Wr + 640, br + 80,
                                     h0_s1, h1_s1, h2_s1, uR, scR, idxR,
                                     start_row, deg_row, a0, N);

  // ---- readout fwd + bwd (includes block-1 h0 update; emits g0, ga0b1) ----
  k_readout_bwd<<<NB_READOUT, BLK, 0, stream>>>(h0_s1, a0, W_read, W1, b1, W2, b2,
                                                W_out + 768, g0, ga0b1, partials, N);
  k_energy<<<1, 128, 0, stream>>>(partials, NB_READOUT, energy);

  // ---- backward block 1 (writes g0+=, g1, g2) ----
  k_bwd_b1_col<<<PBLK, BLK, 0, stream>>>(Wr + 640, br + 80,
                                         h0_s1, h1_s1, h2_s1, ga0b1,
                                         uC, scC, idxC, start_col, deg_col,
                                         g0, g1, g2, dv_c, N);

  // ---- backward block 0 ----
  k_ga<<<cdiv(N*16, BLK), BLK, 0, stream>>>(g0, g1, g2, W_out, a0, a1, a2, N);
  k_bwd_b0_row<<<PBLK, BLK, 0, stream>>>(Wr, br, h0_s0,
                                         a0, a1, a2, uR, scR, idxR,
                                         start_row, deg_row, dv_r, N);

  // ---- force assembly ----
  k_force<<<cdiv(N*16, BLK), BLK, 0, stream>>>(start_row, deg_row, idxR,
                                               start_col, deg_col, idxC,
                                               dv_c, dv_r, force, N);
}

// Round 16
// 448.538 us; speedup vs baseline: 1.0116x; 1.0116x over previous
//
#include <hip/hip_runtime.h>
#include <math.h>

#ifndef M_PI
#define M_PI 3.14159265358979323846
#endif

static inline int cdiv(int a, int b){ return (a + b - 1) / b; }

#define SQRT3f  1.7320508075688772f
#define SQRT5f  2.23606797749979f
#define SQRT15f 3.872983346207417f
#define KRADf   0.6324555320336759f      /* sqrt(2/R_MAX), R_MAX=5 */
#define PI5f    0.6283185307179586f      /* pi/5 */
#define KPI5f   (KRADf * PI5f)
#define CSH2f   (0.5f*SQRT5f)            /* sh2[2] const */
#define CSH4f   (0.5f*SQRT15f)           /* sh2[4] const */

// ---------------------------------------------------------------------------
// R15 post-mortem: 2-deep gather prefetch FALSIFIED (VGPR 60->64, +3us on
// bwd_b1_col, no spill): gathers were already hidden by 8-wave TLP; idle is
// issue-slot contention, not exposure. EXACT REVERT to R14 (450.0us best).
// R14 = session fixpoint: all register-safe instruction cuts (monomial/SH
// const folding, merged P/Q, even/odd Chebyshev, fwd-side node-update fold)
// + memory-layout fixes (int2 idx merge, independent-line scatter stores,
// dv streams + separate k_force). Structural floor: edge loops at 60 VGPR
// = 8 waves/SIMD HW cap, 63-67% VALUBusy, 0 conflicts, ~9% HBM — remaining
// time is VALU issue of the per-edge math (fixed by the model) + scheduling.
// Measured regressions (do NOT retry): launch_bounds either direction
// (r2/r4), scattered force atomics (r5, +84MB RMW), bwd-side epilogue folds
// (r7-r9, spill at 64-tier), same-line packed stores (r13), 2-deep gather
// prefetch (r15).
// ---------------------------------------------------------------------------

__device__ __forceinline__ float grp16_sum(float v){
  v += __shfl_xor(v, 1, 64);
  v += __shfl_xor(v, 2, 64);
  v += __shfl_xor(v, 4, 64);
  v += __shfl_xor(v, 8, 64);
  return v;
}
__device__ __forceinline__ float xgrp_sum(float v){    // across 4 edge-groups
  v += __shfl_xor(v, 16, 64);
  v += __shfl_xor(v, 32, 64);
  return v;
}

// raw second-order monomials: {xy, yz, 3z^2-1, xz, x^2-y^2}
__device__ __forceinline__ void base2_from_u(float ux, float uy, float uz, float* b2)
{
  float z2 = uz*uz, x2 = ux*ux, y2 = uy*uy;
  b2[0] = ux*uy;
  b2[1] = uy*uz;
  b2[2] = fmaf(z2, 3.f, -1.f);
  b2[3] = ux*uz;
  b2[4] = x2 - y2;
}

// ---------------------------------------------------------------------------
// Degree histogram (E-parallel)
// ---------------------------------------------------------------------------
__global__ void k_hist(const int* __restrict__ ei, int E,
                       int* __restrict__ deg_row, int* __restrict__ deg_col)
{
  int e = blockIdx.x * blockDim.x + threadIdx.x;
  if (e >= E) return;
  atomicAdd(&deg_row[ei[e]], 1);
  atomicAdd(&deg_col[ei[E + e]], 1);
}

// ---------------------------------------------------------------------------
// Scan-free segment allocation: wave-aggregated atomicAdd on global cursors.
// ---------------------------------------------------------------------------
__global__ void k_alloc(const int* __restrict__ deg_row, const int* __restrict__ deg_col,
                        int* __restrict__ start_row, int* __restrict__ cur_row,
                        int* __restrict__ start_col, int* __restrict__ cur_col,
                        int* __restrict__ cursors, int N)
{
  int idx = blockIdx.x * blockDim.x + threadIdx.x;
  int lane = threadIdx.x & 63;
  #pragma unroll
  for (int which = 0; which < 2; which++) {
    const int* deg = which ? deg_col : deg_row;
    int* start = which ? start_col : start_row;
    int* cur   = which ? cur_col   : cur_row;
    int v = (idx < N) ? deg[idx] : 0;
    int incl = v;
    #pragma unroll
    for (int d = 1; d < 64; d <<= 1) {
      int y = __shfl_up(incl, d, 64);
      if (lane >= d) incl += y;
    }
    int wtot = __shfl(incl, 63, 64);
    int base = 0;
    if (lane == 63) base = atomicAdd(&cursors[which], wtot);
    base = __shfl(base, 63, 64);
    if (idx < N) { int st = base + incl - v; start[idx] = st; cur[idx] = st; }
  }
}

// ---------------------------------------------------------------------------
// Scatter + compact geometry in BOTH CSR orders. Separate u/sc streams
// (independent lines, parallel stores) + merged idx int2 (one 8B store).
// ---------------------------------------------------------------------------
__global__ void k_scatter_geom(const float* __restrict__ pos, const int* __restrict__ ei, int E,
                               int* __restrict__ cur_row, int* __restrict__ cur_col,
                               float4* __restrict__ uR, float2* __restrict__ scR,
                               float4* __restrict__ uC, float2* __restrict__ scC,
                               int2* __restrict__ idxR, int2* __restrict__ idxC)
{
  int e = blockIdx.x * blockDim.x + threadIdx.x;
  if (e >= E) return;
  int row = ei[e], col = ei[E + e];
  int pr = atomicAdd(&cur_row[row], 1);
  int pc = atomicAdd(&cur_col[col], 1);
  idxR[pr] = make_int2(col, pc);
  idxC[pc] = make_int2(row, pr);

  float px = pos[row*3+0] - pos[col*3+0];
  float py = pos[row*3+1] - pos[col*3+1];
  float pz = pos[row*3+2] - pos[col*3+2];
  float r2 = px*px + py*py + pz*pz + 1e-12f;
  float r = sqrtf(r2);
  float inv_r = 1.0f / r;
  float ux = px*inv_r, uy = py*inv_r, uz = pz*inv_r;
  float s1, c1;
  sincosf(r * PI5f, &s1, &c1);
  float4 u4 = make_float4(ux, uy, uz, inv_r);
  float2 sc = make_float2(s1, c1);
  uR[pr] = u4; scR[pr] = sc;
  uC[pc] = u4; scC[pc] = sc;
}

// ---------------------------------------------------------------------------
// h0_init[n,:] = emb[z[n],:] @ W_init
// ---------------------------------------------------------------------------
__global__ void k_node_init(const float* __restrict__ emb, const int* __restrict__ z,
                            const float* __restrict__ W_init, float* __restrict__ h0, int N)
{
  __shared__ float sW[256];
  if (threadIdx.x < 256) sW[threadIdx.x] = W_init[threadIdx.x];
  __syncthreads();
  int n = blockIdx.x * blockDim.x + threadIdx.x;
  if (n >= N) return;
  const float* e = emb + z[n]*16;
  float ev[16];
  #pragma unroll
  for (int k = 0; k < 16; k++) ev[k] = e[k];
  #pragma unroll
  for (int c = 0; c < 16; c++) {
    float s = 0.f;
    #pragma unroll
    for (int k = 0; k < 16; k++) s += ev[k] * sW[k*16+c];
    h0[n*16+c] = s;
  }
}

// ---------------------------------------------------------------------------
// Forward block 0 — persistent wave per node, 16-lane; node-update folded;
// even/odd split Chebyshev.
// ---------------------------------------------------------------------------
__global__ void k_fwd_b0(const float* __restrict__ Wr, const float* __restrict__ br,
                         const float* __restrict__ h0_in,
                         const float4* __restrict__ uR, const float2* __restrict__ scR,
                         const int2* __restrict__ idxR,
                         const int* __restrict__ start_row, const int* __restrict__ deg_row,
                         const float* __restrict__ U,      // W_out block0: U0|U1|U2
                         float* __restrict__ h0_out, float* __restrict__ h1_out,
                         float* __restrict__ h2_out, int N)
{
  __shared__ float sU[768];
  for (int t = threadIdx.x; t < 768; t += blockDim.x) sU[t] = U[t];
  __syncthreads();

  int wid = (blockIdx.x * blockDim.x + threadIdx.x) >> 6;
  int nw  = (gridDim.x * blockDim.x) >> 6;
  int lane = threadIdx.x & 63;
  int g = lane >> 4, c = lane & 15;
  int gbase = lane & 48;
  float wr0[8], wr1[8], wr2[8];
  #pragma unroll
  for (int k = 0; k < 8; k++) {
    wr0[k] = Wr[k*80 + c];
    wr1[k] = Wr[k*80 + 16 + c];
    wr2[k] = Wr[k*80 + 32 + c];
  }
  float b0v = br[c], b1v = br[16 + c], b2v = br[32 + c];

  for (int n = wid; n < N; n += nw) {
    float acc0 = 0.f, acc1[3] = {0.f,0.f,0.f}, acc2[5] = {0.f,0.f,0.f,0.f,0.f};

    int i0 = start_row[n] + g, i1 = start_row[n] + deg_row[n];
    float4 Un = {0,0,0,0}; float2 SCn = {0,0};
    float h0n = 0.f; int cB = 0;
    if (i0 < i1) {
      int cA = idxR[i0].x;
      cB = (i0+4 < i1) ? idxR[i0+4].x : 0;
      Un = uR[i0]; SCn = scR[i0];
      h0n = h0_in[cA*16 + c];
    }
    for (int i = i0; i < i1; i += 4) {
      float4 U4 = Un; float2 SC = SCn;
      float h0c = h0n;
      if (i+4 < i1) {
        Un = uR[i+4]; SCn = scR[i+4];
        h0n = h0_in[cB*16 + c];           // address ready (cB loaded last iter)
        cB = (i+8 < i1) ? idxR[i+8].x : 0;  // prefetch index 2 ahead
      }
      // even/odd Chebyshev + w-dot: chains A={s1,s3,s5,s7}, B={s2,s4,s6,s8}
      float Ki = KRADf * U4.w;
      float tc = 2.f * SC.y;
      float c2m = fmaf(tc, tc, -2.f);     // 2*cos(2θ)
      float sA = SC.x, sAp = -SC.x;       // s1, s_{-1}
      float sB = tc * SC.x, sBp = 0.f;    // s2, s0
      float w0 = b0v, w1 = b1v, w2 = b2v;
      #pragma unroll
      for (int j = 0; j < 4; j++) {
        float radA = Ki * sA;
        float radB = Ki * sB;
        w0 += radA*wr0[2*j] + radB*wr0[2*j+1];
        w1 += radA*wr1[2*j] + radB*wr1[2*j+1];
        w2 += radA*wr2[2*j] + radB*wr2[2*j+1];
        float sAn = fmaf(c2m, sA, -sAp); sAp = sA; sA = sAn;
        float sBn = fmaf(c2m, sB, -sBp); sBp = sB; sB = sBn;
      }
      float b2m[5];
      base2_from_u(U4.x, U4.y, U4.z, b2m);
      acc0 += w0*h0c;
      float wh1 = w1*h0c, wh2 = w2*h0c;
      acc1[0] += wh1*U4.x; acc1[1] += wh1*U4.y; acc1[2] += wh1*U4.z;
      #pragma unroll
      for (int m = 0; m < 5; m++) acc2[m] += wh2*b2m[m];
    }
    acc0 = xgrp_sum(acc0);
    #pragma unroll
    for (int m = 0; m < 3; m++) acc1[m] = xgrp_sum(acc1[m]);
    #pragma unroll
    for (int m = 0; m < 5; m++) acc2[m] = xgrp_sum(acc2[m]);

    // ---- folded node update, component-at-a-time.
    {
      float o = 0.f;
      #pragma unroll
      for (int j = 0; j < 4; j++) {
        int cs = (g << 2) + j;
        o = fmaf(__shfl(acc0, gbase + cs, 64), sU[cs*16 + c], o);
      }
      o = xgrp_sum(o);
      if (g == 0) h0_out[n*16 + c] = h0_in[n*16 + c] + o;
    }
    #pragma unroll
    for (int m = 0; m < 3; m++) {
      float o = 0.f;
      #pragma unroll
      for (int j = 0; j < 4; j++) {
        int cs = (g << 2) + j;
        o = fmaf(__shfl(acc1[m], gbase + cs, 64), sU[256 + cs*16 + c], o);
      }
      o = xgrp_sum(o);
      if (g == 1) h1_out[n*48 + c*3 + m] = SQRT3f*o;
    }
    #pragma unroll
    for (int m = 0; m < 5; m++) {
      float o = 0.f;
      #pragma unroll
      for (int j = 0; j < 4; j++) {
        int cs = (g << 2) + j;
        o = fmaf(__shfl(acc2[m], gbase + cs, 64), sU[512 + cs*16 + c], o);
      }
      o = xgrp_sum(o);
      if (g == 2) {
        const float csh[5] = {SQRT15f, SQRT15f, CSH2f, SQRT15f, CSH4f};
        h2_out[n*80 + c*5 + m] = csh[m]*o;
      }
    }
  }
}

// ---------------------------------------------------------------------------
// Forward block 1 (last) — persistent wave per node, 16-lane, pipelined idx;
// even/odd split Chebyshev.
// ---------------------------------------------------------------------------
__global__ void k_fwd_b1(const float* __restrict__ Wr, const float* __restrict__ br,
                         const float* __restrict__ h0_in, const float* __restrict__ h1_in,
                         const float* __restrict__ h2_in,
                         const float4* __restrict__ uR, const float2* __restrict__ scR,
                         const int2* __restrict__ idxR,
                         const int* __restrict__ start_row, const int* __restrict__ deg_row,
                         float* __restrict__ a0, int N)
{
  int wid = (blockIdx.x * blockDim.x + threadIdx.x) >> 6;
  int nw  = (gridDim.x * blockDim.x) >> 6;
  int lane = threadIdx.x & 63;
  int g = lane >> 4, c = lane & 15;
  float wr0[8], wr3[8], wr4[8];
  #pragma unroll
  for (int k = 0; k < 8; k++) {
    wr0[k] = Wr[k*80 + c];
    wr3[k] = SQRT3f*Wr[k*80 + 48 + c];   // SQRT3 fold: w3' = SQRT3*w3
    wr4[k] = Wr[k*80 + 64 + c];
  }
  float b0v = br[c], b3v = SQRT3f*br[48 + c], b4v = br[64 + c];

  for (int n = wid; n < N; n += nw) {
    float acc0 = 0.f;
    int i0 = start_row[n] + g, i1 = start_row[n] + deg_row[n];
    float4 Un = {0,0,0,0}; float2 SCn = {0,0};
    float h0n = 0.f, h1n[3] = {0,0,0}, h2n[5] = {0,0,0,0,0};
    int cB = 0;
    if (i0 < i1) {
      int cA = idxR[i0].x;
      cB = (i0+4 < i1) ? idxR[i0+4].x : 0;
      Un = uR[i0]; SCn = scR[i0];
      h0n = h0_in[cA*16 + c];
      #pragma unroll
      for (int m = 0; m < 3; m++) h1n[m] = h1_in[cA*48 + c*3 + m];
      #pragma unroll
      for (int m = 0; m < 5; m++) h2n[m] = h2_in[cA*80 + c*5 + m];
    }
    for (int i = i0; i < i1; i += 4) {
      float4 U = Un; float2 SC = SCn;
      float h0c = h0n;
      float h1c[3], h2c[5];
      #pragma unroll
      for (int m = 0; m < 3; m++) h1c[m] = h1n[m];
      #pragma unroll
      for (int m = 0; m < 5; m++) h2c[m] = h2n[m];
      if (i+4 < i1) {
        Un = uR[i+4]; SCn = scR[i+4];
        h0n = h0_in[cB*16 + c];
        #pragma unroll
        for (int m = 0; m < 3; m++) h1n[m] = h1_in[cB*48 + c*3 + m];
        #pragma unroll
        for (int m = 0; m < 5; m++) h2n[m] = h2_in[cB*80 + c*5 + m];
        cB = (i+8 < i1) ? idxR[i+8].x : 0;
      }
      // even/odd Chebyshev + w-dot
      float Ki = KRADf * U.w;
      float tc = 2.f * SC.y;
      float c2m = fmaf(tc, tc, -2.f);
      float sA = SC.x, sAp = -SC.x;
      float sB = tc * SC.x, sBp = 0.f;
      float w0 = b0v, w3 = b3v, w4 = b4v;
      #pragma unroll
      for (int j = 0; j < 4; j++) {
        float radA = Ki * sA;
        float radB = Ki * sB;
        w0 += radA*wr0[2*j] + radB*wr0[2*j+1];
        w3 += radA*wr3[2*j] + radB*wr3[2*j+1];
        w4 += radA*wr4[2*j] + radB*wr4[2*j+1];
        float sAn = fmaf(c2m, sA, -sAp); sAp = sA; sA = sAn;
        float sBn = fmaf(c2m, sB, -sBp); sBp = sB; sB = sBn;
      }
      float b2[5];
      base2_from_u(U.x, U.y, U.z, b2);
      float S1 = h1c[0]*U.x + h1c[1]*U.y + h1c[2]*U.z;   // SQRT3 folded in w3
      float A  = h2c[0]*b2[0] + h2c[1]*b2[1] + h2c[3]*b2[3];
      float B  = CSH2f*(h2c[2]*b2[2]) + CSH4f*(h2c[4]*b2[4]);
      float S2 = fmaf(SQRT15f, A, B);
      acc0 += w0*h0c + w3*S1 + w4*S2;
    }
    acc0 = xgrp_sum(acc0);
    if (g == 0) a0[n*16 + c] = acc0;
  }
}

// ---------------------------------------------------------------------------
// Readout fwd + bwd fused (unchanged).
// ---------------------------------------------------------------------------
__global__ void __launch_bounds__(256, 1)
k_readout_bwd(const float* __restrict__ h0s1, const float* __restrict__ a0in,
              const float* __restrict__ W_read,
              const float* __restrict__ W1, const float* __restrict__ b1,
              const float* __restrict__ W2, const float* __restrict__ b2,
              const float* __restrict__ U0b1,
              float* __restrict__ g0, float* __restrict__ ga0,
              float* __restrict__ partials, int N)
{
  __shared__ float sWr[256], sW1[256], sU[256], sb1[16], sW2[16], sb2;
  __shared__ float swave[4];
  {
    int t = threadIdx.x;
    if (t < 256) { sWr[t] = W_read[t]; sW1[t] = W1[t]; sU[t] = U0b1[t]; }
    if (t < 16)  { sb1[t] = b1[t]; sW2[t] = W2[t]; }
    if (t == 0)  sb2 = b2[0];
  }
  __syncthreads();
  int n = blockIdx.x * blockDim.x + threadIdx.x;
  float site = 0.f;
  if (n < N) {
    float h[16], av[16], inv[16], dt[16], g0v[16];
    #pragma unroll
    for (int d = 0; d < 16; d++) av[d] = a0in[n*16 + d];
    #pragma unroll
    for (int d = 0; d < 16; d++) {
      float s = h0s1[n*16 + d];
      #pragma unroll
      for (int cc = 0; cc < 16; cc++) s += av[cc] * sU[cc*16 + d];
      h[d] = s;
    }
    #pragma unroll
    for (int j = 0; j < 16; j++) {
      float s = 0.f;
      #pragma unroll
      for (int d = 0; d < 16; d++) s += h[d] * sWr[d*16 + j];
      inv[j] = s;
    }
    site = sb2;
    #pragma unroll
    for (int c = 0; c < 16; c++) {
      float t = sb1[c];
      #pragma unroll
      for (int j = 0; j < 16; j++) t += inv[j] * sW1[j*16 + c];
      float sg = 1.f / (1.f + expf(-t));
      float w2v = sW2[c];
      site += t * sg * w2v;
      dt[c] = w2v * sg * (1.f + t * (1.f - sg));
    }
    float dinv[16];
    #pragma unroll
    for (int j = 0; j < 16; j++) {
      float s = 0.f;
      #pragma unroll
      for (int c = 0; c < 16; c++) s += dt[c] * sW1[j*16 + c];
      dinv[j] = s;
    }
    #pragma unroll
    for (int d = 0; d < 16; d++) {
      float s = 0.f;
      #pragma unroll
      for (int j = 0; j < 16; j++) s += dinv[j] * sWr[d*16 + j];
      g0v[d] = s;
      g0[n*16 + d] = s;
    }
    #pragma unroll
    for (int c = 0; c < 16; c++) {
      float s = 0.f;
      #pragma unroll
      for (int d = 0; d < 16; d++) s += g0v[d] * sU[c*16 + d];
      ga0[n*16 + c] = s;
    }
  }
  #pragma unroll
  for (int off = 32; off; off >>= 1) site += __shfl_down(site, off, 64);
  int wave = threadIdx.x >> 6;
  if ((threadIdx.x & 63) == 0) swave[wave] = site;
  __syncthreads();
  if (threadIdx.x == 0)
    partials[blockIdx.x] = swave[0] + swave[1] + swave[2] + swave[3];
}

// Sum per-block partials into energy (single tiny block).
__global__ void k_energy(const float* __restrict__ partials, int nb,
                         float* __restrict__ energy)
{
  int t = threadIdx.x;           // 128 threads (2 waves)
  float s = 0.f;
  for (int i = t; i < nb; i += 128) s += partials[i];
  #pragma unroll
  for (int off = 32; off; off >>= 1) s += __shfl_down(s, off, 64);
  __shared__ float sw[2];
  if ((t & 63) == 0) sw[t >> 6] = s;
  __syncthreads();
  if (t == 0) energy[0] = sw[0] + sw[1];
}

// ---------------------------------------------------------------------------
// ga = g @ U^T (full, for block 0 backward).
// ---------------------------------------------------------------------------
__global__ void k_ga(const float* __restrict__ g0, const float* __restrict__ g1,
                     const float* __restrict__ g2, const float* __restrict__ U,
                     float* __restrict__ ga0, float* __restrict__ ga1, float* __restrict__ ga2,
                     int N)
{
  int idx = blockIdx.x * blockDim.x + threadIdx.x;
  int n = idx >> 4, c = idx & 15;
  if (n >= N) return;
  const float* U0 = U;
  const float* U1 = U + 256;
  const float* U2 = U + 512;
  float s = 0.f;
  #pragma unroll
  for (int d = 0; d < 16; d++) s += g0[n*16 + d] * U0[c*16 + d];
  ga0[n*16 + c] = s;
  float v1[3] = {0.f, 0.f, 0.f};
  #pragma unroll
  for (int d = 0; d < 16; d++) {
    float u = U1[c*16 + d];
    #pragma unroll
    for (int m = 0; m < 3; m++) v1[m] += g1[n*48 + d*3 + m] * u;
  }
  #pragma unroll
  for (int m = 0; m < 3; m++) ga1[n*48 + c*3 + m] = v1[m];
  float v2[5] = {0.f, 0.f, 0.f, 0.f, 0.f};
  #pragma unroll
  for (int d = 0; d < 16; d++) {
    float u = U2[c*16 + d];
    #pragma unroll
    for (int m = 0; m < 5; m++) v2[m] += g2[n*80 + d*5 + m] * u;
  }
  #pragma unroll
  for (int m = 0; m < 5; m++) ga2[n*80 + c*5 + m] = v2[m];
}

// ---------------------------------------------------------------------------
// Backward block 1, col-centric — persistent wave per node, 16-lane,
// pipelined idx.
// ---------------------------------------------------------------------------
__global__ void k_bwd_b1_col(const float* __restrict__ Wr, const float* __restrict__ br,
                             const float* __restrict__ h0_in, const float* __restrict__ h1_in,
                             const float* __restrict__ h2_in,
                             const float* __restrict__ ga0,
                             const float4* __restrict__ uC, const float2* __restrict__ scC,
                             const int2* __restrict__ idxC,
                             const int* __restrict__ start_col, const int* __restrict__ deg_col,
                             float* __restrict__ g0, float* __restrict__ g1, float* __restrict__ g2,
                             float* __restrict__ dv_col, int N)
{
  int wid = (blockIdx.x * blockDim.x + threadIdx.x) >> 6;
  int nw  = (gridDim.x * blockDim.x) >> 6;
  int lane = threadIdx.x & 63;
  int g = lane >> 4, c = lane & 15;
  float wr0[8], wr3[8], wr4[8];
  #pragma unroll
  for (int k = 0; k < 8; k++) {
    wr0[k] = Wr[k*80 + c];
    wr3[k] = Wr[k*80 + 48 + c];
    wr4[k] = Wr[k*80 + 64 + c];
  }
  float b0v = br[c], b3v = br[48 + c], b4v = br[64 + c];

  for (int n = wid; n < N; n += nw) {
    float h0c = h0_in[n*16 + c];
    float h1s[3], h2s[5];
    #pragma unroll
    for (int m = 0; m < 3; m++) h1s[m] = SQRT3f * h1_in[n*48 + c*3 + m];
    h2s[0] = SQRT15f * h2_in[n*80 + c*5 + 0];
    h2s[1] = SQRT15f * h2_in[n*80 + c*5 + 1];
    h2s[2] = CSH2f   * h2_in[n*80 + c*5 + 2];
    h2s[3] = SQRT15f * h2_in[n*80 + c*5 + 3];
    h2s[4] = CSH4f   * h2_in[n*80 + c*5 + 4];

    float accg0 = 0.f, accg1[3] = {0.f,0.f,0.f}, accg2[5] = {0.f,0.f,0.f,0.f,0.f};

    int i0 = start_col[n] + g, i1 = start_col[n] + deg_col[n];
    float4 Un = {0,0,0,0}; float2 SCn = {0,0};
    float dm0n = 0.f; int rB = 0;
    if (i0 < i1) {
      int rA = idxC[i0].x;
      rB = (i0+4 < i1) ? idxC[i0+4].x : 0;
      Un = uC[i0]; SCn = scC[i0];
      dm0n = ga0[rA*16 + c];
    }
    for (int i = i0; i < i1; i += 4) {
      float4 U4 = Un; float2 SC = SCn;
      float dm0 = dm0n;
      if (i+4 < i1) {
        Un = uC[i+4]; SCn = scC[i+4];
        dm0n = ga0[rB*16 + c];
        rB = (i+8 < i1) ? idxC[i+8].x : 0;
      }
      float ux = U4.x, uy = U4.y, uz = U4.z, inv_r = U4.w;
      float b2[5];
      base2_from_u(ux, uy, uz, b2);

      float S1 = h1s[0]*ux + h1s[1]*uy + h1s[2]*uz;
      float S2 = h2s[0]*b2[0] + h2s[1]*b2[1] + h2s[2]*b2[2]
               + h2s[3]*b2[3] + h2s[4]*b2[4];

      float dw0 = dm0 * h0c;
      float dw3 = dm0 * S1;
      float dw4 = dm0 * S2;

      // merged Chebyshev + w-dot + t-dot + P/Q
      float Ki = KRADf * inv_r;
      float tcv = 2.f * SC.y;
      float sprev = 0.f, s = SC.x, cprev = 1.f, cc = SC.y;
      float w0 = b0v, w3 = b3v, w4 = b4v;
      float P = 0.f, Q = 0.f;
      #pragma unroll
      for (int k = 0; k < 8; k++) {
        float rad = Ki * s;
        w0 += rad*wr0[k]; w3 += rad*wr3[k]; w4 += rad*wr4[k];
        float t = dw0*wr0[k] + dw3*wr3[k] + dw4*wr4[k];
        P = fmaf(t*cc, (float)(k+1), P);
        Q = fmaf(t, rad, Q);
        float sn = tcv*s - sprev; sprev = s; s = sn;
        float cn = tcv*cc - cprev; cprev = cc; cc = cn;
      }

      float t3 = dm0 * w3, t4 = dm0 * w4;
      accg0 += dm0 * w0;
      accg1[0] += t3*ux; accg1[1] += t3*uy; accg1[2] += t3*uz;
      #pragma unroll
      for (int m = 0; m < 5; m++) accg2[m] += t4*b2[m];

      float q1x = t3*h1s[0], q1y = t3*h1s[1], q1z = t3*h1s[2];
      float q0 = t4*h2s[0], q1 = t4*h2s[1], q2 = t4*h2s[2], q3 = t4*h2s[3], q4 = t4*h2s[4];
      float q4d = q4 + q4;
      float q2h = 6.f*q2;
      float gr = (KPI5f*P - Q) * inv_r;
      float gux = q1x + uy*q0 + uz*q3 + ux*q4d;
      float guy = q1y + ux*q0 + uz*q1 - uy*q4d;
      float guz = q1z + uy*q1 + uz*q2h + ux*q3;

      gr  = grp16_sum(gr);
      gux = grp16_sum(gux);
      guy = grp16_sum(guy);
      guz = grp16_sum(guz);

      if (c == 0) {
        float gdotu = gux*ux + guy*uy + guz*uz;
        dv_col[i*3+0] = gr*ux + (gux - gdotu*ux)*inv_r;
        dv_col[i*3+1] = gr*uy + (guy - gdotu*uy)*inv_r;
        dv_col[i*3+2] = gr*uz + (guz - gdotu*uz)*inv_r;
      }
    }
    accg0 = xgrp_sum(accg0);
    #pragma unroll
    for (int m = 0; m < 3; m++) accg1[m] = xgrp_sum(accg1[m]);
    #pragma unroll
    for (int m = 0; m < 5; m++) accg2[m] = xgrp_sum(accg2[m]);
    if (g == 0) {
      g0[n*16 + c] += accg0;
      g1[n*48 + c*3 + 0] = SQRT3f*accg1[0];
      g1[n*48 + c*3 + 1] = SQRT3f*accg1[1];
      g1[n*48 + c*3 + 2] = SQRT3f*accg1[2];
      g2[n*80 + c*5 + 0] = SQRT15f*accg2[0];
      g2[n*80 + c*5 + 1] = SQRT15f*accg2[1];
      g2[n*80 + c*5 + 2] = CSH2f  *accg2[2];
      g2[n*80 + c*5 + 3] = SQRT15f*accg2[3];
      g2[n*80 + c*5 + 4] = CSH4f  *accg2[4];
    }
  }
}

// ---------------------------------------------------------------------------
// Backward block 0, row-centric — persistent wave per node, 16-lane,
// pipelined idx; even/odd sin+cos split.
// ---------------------------------------------------------------------------
__global__ void k_bwd_b0_row(const float* __restrict__ Wr, const float* __restrict__ br,
                             const float* __restrict__ h0_in,
                             const float* __restrict__ ga0, const float* __restrict__ ga1,
                             const float* __restrict__ ga2,
                             const float4* __restrict__ uR, const float2* __restrict__ scR,
                             const int2* __restrict__ idxR,
                             const int* __restrict__ start_row, const int* __restrict__ deg_row,
                             float* __restrict__ dv_row, int N)
{
  int wid = (blockIdx.x * blockDim.x + threadIdx.x) >> 6;
  int nw  = (gridDim.x * blockDim.x) >> 6;
  int lane = threadIdx.x & 63;
  int g = lane >> 4, c = lane & 15;
  float wr0[8], wr1[8], wr2[8];
  #pragma unroll
  for (int k = 0; k < 8; k++) {
    wr0[k] = Wr[k*80 + c];
    wr1[k] = Wr[k*80 + 16 + c];
    wr2[k] = Wr[k*80 + 32 + c];
  }
  float b1v = br[16 + c], b2v = br[32 + c];

  for (int n = wid; n < N; n += nw) {
    float dm0 = ga0[n*16 + c];
    float dm1s[3], dm2s[5];
    #pragma unroll
    for (int m = 0; m < 3; m++) dm1s[m] = SQRT3f * ga1[n*48 + c*3 + m];
    dm2s[0] = SQRT15f * ga2[n*80 + c*5 + 0];
    dm2s[1] = SQRT15f * ga2[n*80 + c*5 + 1];
    dm2s[2] = CSH2f   * ga2[n*80 + c*5 + 2];
    dm2s[3] = SQRT15f * ga2[n*80 + c*5 + 3];
    dm2s[4] = CSH4f   * ga2[n*80 + c*5 + 4];

    int i0 = start_row[n] + g, i1 = start_row[n] + deg_row[n];
    float4 Un = {0,0,0,0}; float2 SCn = {0,0};
    float h0n = 0.f; int cB = 0;
    if (i0 < i1) {
      int cA = idxR[i0].x;
      cB = (i0+4 < i1) ? idxR[i0+4].x : 0;
      Un = uR[i0]; SCn = scR[i0];
      h0n = h0_in[cA*16 + c];
    }
    for (int i = i0; i < i1; i += 4) {
      float4 U = Un; float2 SC = SCn;
      float h0c = h0n;
      if (i+4 < i1) {
        Un = uR[i+4]; SCn = scR[i+4];
        h0n = h0_in[cB*16 + c];
        cB = (i+8 < i1) ? idxR[i+8].x : 0;
      }
      float ux = U.x, uy = U.y, uz = U.z, inv_r = U.w;
      float b2[5];
      base2_from_u(ux, uy, uz, b2);

      float T1 = dm1s[0]*ux + dm1s[1]*uy + dm1s[2]*uz;
      float T2 = dm2s[0]*b2[0] + dm2s[1]*b2[1] + dm2s[2]*b2[2]
               + dm2s[3]*b2[3] + dm2s[4]*b2[4];

      float dw0 = dm0 * h0c;
      float dw1 = h0c * T1;
      float dw2 = h0c * T2;

      // even/odd merged Chebyshev (sin+cos) + w-dot + t-dot + P/Q.
      float Ki = KRADf * inv_r;
      float tcv = 2.f * SC.y;
      float c2m = fmaf(tcv, tcv, -2.f);        // 2*cos(2θ)
      float sA = SC.x,        sAp = -SC.x;     // s1, s_{-1}
      float cA = SC.y,        cAp =  SC.y;     // c1, c_{-1}
      float sB = tcv * SC.x,  sBp = 0.f;       // s2, s0
      float cB2 = fmaf(tcv, SC.y, -1.f), cBp = 1.f;  // c2, c0
      float w1 = b1v, w2v = b2v;
      float P = 0.f, Q = 0.f;
      #pragma unroll
      for (int j = 0; j < 4; j++) {
        float radA = Ki * sA;
        float radB = Ki * sB;
        w1  += radA*wr1[2*j] + radB*wr1[2*j+1];
        w2v += radA*wr2[2*j] + radB*wr2[2*j+1];
        float tA = dw0*wr0[2*j]   + dw1*wr1[2*j]   + dw2*wr2[2*j];
        float tB = dw0*wr0[2*j+1] + dw1*wr1[2*j+1] + dw2*wr2[2*j+1];
        P = fmaf(tA*cA, (float)(2*j+1), P);
        P = fmaf(tB*cB2, (float)(2*j+2), P);
        Q = fmaf(tA, radA, Q);
        Q = fmaf(tB, radB, Q);
        float sAn = fmaf(c2m, sA, -sAp); sAp = sA; sA = sAn;
        float cAn = fmaf(c2m, cA, -cAp); cAp = cA; cA = cAn;
        float sBn = fmaf(c2m, sB, -sBp); sBp = sB; sB = sBn;
        float cBn = fmaf(c2m, cB2, -cBp); cBp = cB2; cB2 = cBn;
      }

      float w1h = w1*h0c, w2h = w2v*h0c;
      float q1x = dm1s[0]*w1h, q1y = dm1s[1]*w1h, q1z = dm1s[2]*w1h;
      float q0 = dm2s[0]*w2h, q1 = dm2s[1]*w2h, q2 = dm2s[2]*w2h, q3 = dm2s[3]*w2h, q4 = dm2s[4]*w2h;
      float q4d = q4 + q4;
      float q2h = 6.f*q2;
      float gr = (KPI5f*P - Q) * inv_r;
      float gux = q1x + uy*q0 + uz*q3 + ux*q4d;
      float guy = q1y + ux*q0 + uz*q1 - uy*q4d;
      float guz = q1z + uy*q1 + uz*q2h + ux*q3;

      gr  = grp16_sum(gr);
      gux = grp16_sum(gux);
      guy = grp16_sum(guy);
      guz = grp16_sum(guz);

      if (c == 0) {
        float gdotu = gux*ux + guy*uy + guz*uz;
        dv_row[i*3+0] = gr*ux + (gux - gdotu*ux)*inv_r;
        dv_row[i*3+1] = gr*uy + (guy - gdotu*uy)*inv_r;
        dv_row[i*3+2] = gr*uz + (guz - gdotu*uz)*inv_r;
      }
    }
  }
}

// ---------------------------------------------------------------------------
// Force assembly: 16 lanes per node, coalesced dv-stream reads, no atomics.
// cpos = idxR[i].y ; rpos = idxC[i].y.
// ---------------------------------------------------------------------------
__global__ void k_force(const int* __restrict__ start_row, const int* __restrict__ deg_row,
                        const int2* __restrict__ idxR,
                        const int* __restrict__ start_col, const int* __restrict__ deg_col,
                        const int2* __restrict__ idxC,
                        const float* __restrict__ dv_col, const float* __restrict__ dv_row,
                        float* __restrict__ force, int N)
{
  int idx = blockIdx.x * blockDim.x + threadIdx.x;
  int n = idx >> 4, l = idx & 15;
  if (n >= N) return;
  float fx = 0.f, fy = 0.f, fz = 0.f;
  int c0 = start_col[n], c1 = c0 + deg_col[n];
  for (int i = c0 + l; i < c1; i += 16) {
    int rp = idxC[i].y;
    fx += dv_col[i*3+0] + dv_row[rp*3+0];
    fy += dv_col[i*3+1] + dv_row[rp*3+1];
    fz += dv_col[i*3+2] + dv_row[rp*3+2];
  }
  int r0 = start_row[n], r1 = r0 + deg_row[n];
  for (int i = r0 + l; i < r1; i += 16) {
    int cp = idxR[i].y;
    fx -= dv_row[i*3+0] + dv_col[cp*3+0];
    fy -= dv_row[i*3+1] + dv_col[cp*3+1];
    fz -= dv_row[i*3+2] + dv_col[cp*3+2];
  }
  fx = grp16_sum(fx); fy = grp16_sum(fy); fz = grp16_sum(fz);
  if (l == 0) {
    force[n*3+0] = fx; force[n*3+1] = fy; force[n*3+2] = fz;
  }
}

// ---------------------------------------------------------------------------
extern "C" void kernel_launch(void* const* d_in, const int* in_sizes, int n_in,
                              void* d_out, int out_size, void* d_ws, size_t ws_size,
                              hipStream_t stream)
{
  const float* pos    = (const float*)d_in[0];
  const int*   z      = (const int*)  d_in[1];
  const int*   ei     = (const int*)  d_in[2];
  const float* emb    = (const float*)d_in[3];
  const float* W_init = (const float*)d_in[4];
  const float* Wr     = (const float*)d_in[5];   // (2, 8, 80)
  const float* br     = (const float*)d_in[6];   // (2, 80)
  const float* W_out  = (const float*)d_in[7];   // (2, 3, 16, 16)
  const float* W_read = (const float*)d_in[8];
  const float* W1     = (const float*)d_in[9];
  const float* b1     = (const float*)d_in[10];
  const float* W2     = (const float*)d_in[11];
  const float* b2     = (const float*)d_in[12];

  const int N = in_sizes[0] / 3;
  const int E = in_sizes[2] / 2;

  const int BLK = 256;
  const int NB_READOUT = cdiv(N, BLK);
  // Persistent grid for wave-per-node kernels.
  const int PBLK = (N < 8192) ? cdiv(N, 4) : 2048;

  float* f = (float*)d_ws;
  float4* uR  = (float4*)f; f += (size_t)E*4;
  float4* uC  = (float4*)f; f += (size_t)E*4;
  float2* scR = (float2*)f; f += (size_t)E*2;
  float2* scC = (float2*)f; f += (size_t)E*2;
  float* h0_s0 = f; f += (size_t)N*16;
  float* h0_s1 = f; f += (size_t)N*16;
  float* h1_s1 = f; f += (size_t)N*48;
  float* h2_s1 = f; f += (size_t)N*80;
  float* a0    = f; f += (size_t)N*16;   // fwd_b1 agg, then ga0 for bwd_b0
  float* a1    = f; f += (size_t)N*48;   // ga1
  float* a2    = f; f += (size_t)N*80;   // ga2
  float* ga0b1 = f; f += (size_t)N*16;   // readout's ga0 (dE/da0 block 1)
  float* g0    = f; f += (size_t)N*16;
  float* g1    = f; f += (size_t)N*48;
  float* g2    = f; f += (size_t)N*80;
  float* dv_c  = f; f += (size_t)E*3;    // dv from bwd b1, col order
  float* dv_r  = f; f += (size_t)E*3;    // dv from bwd b0, row order
  float* partials = f; f += (size_t)NB_READOUT;
  int* ip = (int*)f;
  int* cursors   = ip; ip += 2;          // cursors+deg contiguous -> one memset
  int* deg_row   = ip; ip += N;
  int* deg_col   = ip; ip += N;
  int* start_row = ip; ip += N;
  int* start_col = ip; ip += N;
  int* cur_row   = ip; ip += N;
  int* cur_col   = ip; ip += N;
  int2* idxR     = (int2*)ip; ip += (size_t)E*2;  // (col, cpos)
  int2* idxC     = (int2*)ip; ip += (size_t)E*2;  // (row, rpos)

  float* out    = (float*)d_out;
  float* energy = out;
  float* force  = out + 1;

  (void)hipMemsetAsync(cursors, 0, (size_t)(2 + 2*N) * sizeof(int), stream);

  // ---- CSR build (scan-free) + compact geometry in both orders ----
  k_hist<<<cdiv(E, BLK), BLK, 0, stream>>>(ei, E, deg_row, deg_col);
  k_alloc<<<cdiv(N, BLK), BLK, 0, stream>>>(deg_row, deg_col, start_row, cur_row,
                                            start_col, cur_col, cursors, N);
  k_scatter_geom<<<cdiv(E, BLK), BLK, 0, stream>>>(pos, ei, E, cur_row, cur_col,
                                                   uR, scR, uC, scC, idxR, idxC);

  k_node_init<<<cdiv(N, BLK), BLK, 0, stream>>>(emb, z, W_init, h0_s0, N);

  // ---- forward block 0 (node update folded into epilogue) ----
  k_fwd_b0<<<PBLK, BLK, 0, stream>>>(Wr, br, h0_s0, uR, scR, idxR,
                                     start_row, deg_row, W_out,
                                     h0_s1, h1_s1, h2_s1, N);

  // ---- forward block 1 (h0_s2 folded into readout) ----
  k_fwd_b1<<<PBLK, BLK, 0, stream>>>(Wr + 640, br + 80,
                                     h0_s1, h1_s1, h2_s1, uR, scR, idxR,
                                     start_row, deg_row, a0, N);

  // ---- readout fwd + bwd (includes block-1 h0 update; emits g0, ga0b1) ----
  k_readout_bwd<<<NB_READOUT, BLK, 0, stream>>>(h0_s1, a0, W_read, W1, b1, W2, b2,
                                                W_out + 768, g0, ga0b1, partials, N);
  k_energy<<<1, 128, 0, stream>>>(partials, NB_READOUT, energy);

  // ---- backward block 1 (writes g0+=, g1, g2) ----
  k_bwd_b1_col<<<PBLK, BLK, 0, stream>>>(Wr + 640, br + 80,
                                         h0_s1, h1_s1, h2_s1, ga0b1,
                                         uC, scC, idxC, start_col, deg_col,
                                         g0, g1, g2, dv_c, N);

  // ---- backward block 0 ----
  k_ga<<<cdiv(N*16, BLK), BLK, 0, stream>>>(g0, g1, g2, W_out, a0, a1, a2, N);
  k_bwd_b0_row<<<PBLK, BLK, 0, stream>>>(Wr, br, h0_s0,
                                         a0, a1, a2, uR, scR, idxR,
                                         start_row, deg_row, dv_r, N);

  // ---- force assembly ----
  k_force<<<cdiv(N*16, BLK), BLK, 0, stream>>>(start_row, deg_row, idxR,
                                               start_col, deg_col, idxC,
                                               dv_c, dv_r, force, N);
}